// Round 2
// baseline (227.006 us; speedup 1.0000x reference)
//
#include <hip/hip_runtime.h>
#include <stdint.h>

#define NBINS 1000

// ---- sortable encoding for f32 min/max via uint atomics ----
__device__ __forceinline__ unsigned enc_f32(float f) {
    unsigned b = __float_as_uint(f);
    return (b & 0x80000000u) ? ~b : (b | 0x80000000u);
}
__device__ __forceinline__ float dec_f32(unsigned e) {
    unsigned b = (e & 0x80000000u) ? (e ^ 0x80000000u) : ~e;
    return __uint_as_float(b);
}

// W layout (uints): [0]=min_enc [1]=max_enc [2..2+2*NBINS)=final histograms
__global__ void __launch_bounds__(512) init_kernel(unsigned* __restrict__ W) {
    int t = threadIdx.x;
    for (int i = t; i < 2 + 2 * NBINS; i += 512) W[i] = 0u;
    if (t == 0) W[0] = 0xFFFFFFFFu;
}

__global__ void __launch_bounds__(256) minmax_kernel(
        const float* __restrict__ p, const float* __restrict__ t,
        long long n, unsigned* __restrict__ W) {
    long long n4 = n >> 2;
    const float4* p4 = (const float4*)p;
    const float4* t4 = (const float4*)t;
    unsigned emin = 0xFFFFFFFFu, emax = 0u;
    long long idx = (long long)blockIdx.x * blockDim.x + threadIdx.x;
    long long stride = (long long)gridDim.x * blockDim.x;

#define MM1(v) { unsigned e = enc_f32(v); emin = min(emin, e); emax = max(emax, e); }
#define MM4(q) { MM1(q.x) MM1(q.y) MM1(q.z) MM1(q.w) }

    long long i = idx;
    // 4x unrolled: 8 independent float4 loads in flight per iteration
    for (; i + 3 * stride < n4; i += 4 * stride) {
        float4 a0 = p4[i];
        float4 a1 = p4[i + stride];
        float4 a2 = p4[i + 2 * stride];
        float4 a3 = p4[i + 3 * stride];
        float4 b0 = t4[i];
        float4 b1 = t4[i + stride];
        float4 b2 = t4[i + 2 * stride];
        float4 b3 = t4[i + 3 * stride];
        MM4(a0) MM4(a1) MM4(a2) MM4(a3)
        MM4(b0) MM4(b1) MM4(b2) MM4(b3)
    }
    for (; i < n4; i += stride) {
        float4 a = p4[i];
        float4 b = t4[i];
        MM4(a) MM4(b)
    }
    for (long long j = (n4 << 2) + idx; j < n; j += stride) {
        MM1(p[j]) MM1(t[j])
    }

    __shared__ unsigned smin[256];
    __shared__ unsigned smax[256];
    int tid = threadIdx.x;
    smin[tid] = emin; smax[tid] = emax;
    __syncthreads();
    for (int s = 128; s > 0; s >>= 1) {
        if (tid < s) {
            smin[tid] = min(smin[tid], smin[tid + s]);
            smax[tid] = max(smax[tid], smax[tid + s]);
        }
        __syncthreads();
    }
    if (tid == 0) {
        atomicMin(&W[0], smin[0]);
        atomicMax(&W[1], smax[0]);
    }
}

// count of v <= x_j == sum_{k<=j} hist[k] with bin k = clamp(ceil((v-lo)/dx))
__device__ __forceinline__ int binof(float v, float lo, float inv_dx) {
    float u = (v - lo) * inv_dx;
    int k = (int)ceilf(u);
    return min(max(k, 0), NBINS - 1);
}

// 4 LDS sub-copies per histogram, selected by lane&3. Copy stride 1000 words
// = 8-bank rotation, so the 4 copies of a given bin hit banks {0,8,16,24}.
__global__ void __launch_bounds__(256) hist_kernel(
        const float* __restrict__ p, const float* __restrict__ t,
        long long n, unsigned* __restrict__ W) {
    __shared__ unsigned h[8 * NBINS];  // [0..4000)=p copies, [4000..8000)=t copies
    for (int i = threadIdx.x; i < 8 * NBINS; i += blockDim.x) h[i] = 0u;
    __syncthreads();

    float lo = dec_f32(W[0]);
    float hi = dec_f32(W[1]);
    float inv_dx = (float)(NBINS - 1) / (hi - lo);

    int cp = (threadIdx.x & 3) * NBINS;
    int ct = cp + 4 * NBINS;

    long long n4 = n >> 2;
    const float4* p4 = (const float4*)p;
    const float4* t4 = (const float4*)t;
    long long idx = (long long)blockIdx.x * blockDim.x + threadIdx.x;
    long long stride = (long long)gridDim.x * blockDim.x;
    long long i = idx;
    for (; i + stride < n4; i += 2 * stride) {
        float4 a0 = p4[i];
        float4 a1 = p4[i + stride];
        float4 b0 = t4[i];
        float4 b1 = t4[i + stride];
        atomicAdd(&h[cp + binof(a0.x, lo, inv_dx)], 1u);
        atomicAdd(&h[cp + binof(a0.y, lo, inv_dx)], 1u);
        atomicAdd(&h[cp + binof(a0.z, lo, inv_dx)], 1u);
        atomicAdd(&h[cp + binof(a0.w, lo, inv_dx)], 1u);
        atomicAdd(&h[cp + binof(a1.x, lo, inv_dx)], 1u);
        atomicAdd(&h[cp + binof(a1.y, lo, inv_dx)], 1u);
        atomicAdd(&h[cp + binof(a1.z, lo, inv_dx)], 1u);
        atomicAdd(&h[cp + binof(a1.w, lo, inv_dx)], 1u);
        atomicAdd(&h[ct + binof(b0.x, lo, inv_dx)], 1u);
        atomicAdd(&h[ct + binof(b0.y, lo, inv_dx)], 1u);
        atomicAdd(&h[ct + binof(b0.z, lo, inv_dx)], 1u);
        atomicAdd(&h[ct + binof(b0.w, lo, inv_dx)], 1u);
        atomicAdd(&h[ct + binof(b1.x, lo, inv_dx)], 1u);
        atomicAdd(&h[ct + binof(b1.y, lo, inv_dx)], 1u);
        atomicAdd(&h[ct + binof(b1.z, lo, inv_dx)], 1u);
        atomicAdd(&h[ct + binof(b1.w, lo, inv_dx)], 1u);
    }
    for (; i < n4; i += stride) {
        float4 a = p4[i];
        float4 b = t4[i];
        atomicAdd(&h[cp + binof(a.x, lo, inv_dx)], 1u);
        atomicAdd(&h[cp + binof(a.y, lo, inv_dx)], 1u);
        atomicAdd(&h[cp + binof(a.z, lo, inv_dx)], 1u);
        atomicAdd(&h[cp + binof(a.w, lo, inv_dx)], 1u);
        atomicAdd(&h[ct + binof(b.x, lo, inv_dx)], 1u);
        atomicAdd(&h[ct + binof(b.y, lo, inv_dx)], 1u);
        atomicAdd(&h[ct + binof(b.z, lo, inv_dx)], 1u);
        atomicAdd(&h[ct + binof(b.w, lo, inv_dx)], 1u);
    }
    for (long long j = (n4 << 2) + idx; j < n; j += stride) {
        atomicAdd(&h[cp + binof(p[j], lo, inv_dx)], 1u);
        atomicAdd(&h[ct + binof(t[j], lo, inv_dx)], 1u);
    }
    __syncthreads();

    // fold 4 copies and flush straight to the global histogram
    unsigned* Wh = W + 2;
    for (int b = threadIdx.x; b < NBINS; b += blockDim.x) {
        unsigned sp = h[b] + h[NBINS + b] + h[2 * NBINS + b] + h[3 * NBINS + b];
        unsigned st = h[4 * NBINS + b] + h[5 * NBINS + b] + h[6 * NBINS + b] + h[7 * NBINS + b];
        if (sp) atomicAdd(&Wh[b], sp);
        if (st) atomicAdd(&Wh[NBINS + b], st);
    }
}

__global__ void __launch_bounds__(1024) finalize_kernel(
        const unsigned* __restrict__ W, float* __restrict__ out, long long n) {
    __shared__ unsigned s[1024];
    __shared__ float cp[NBINS];
    __shared__ double rd[1024];
    int t = threadIdx.x;

    // inclusive scan of hist_p
    s[t] = (t < NBINS) ? W[2 + t] : 0u;
    __syncthreads();
    for (int off = 1; off < 1024; off <<= 1) {
        unsigned v = (t >= off) ? s[t - off] : 0u;
        __syncthreads();
        s[t] += v;
        __syncthreads();
    }
    if (t < NBINS) cp[t] = (float)s[t];
    __syncthreads();

    // inclusive scan of hist_t
    s[t] = (t < NBINS) ? W[2 + NBINS + t] : 0u;
    __syncthreads();
    for (int off = 1; off < 1024; off <<= 1) {
        unsigned v = (t >= off) ? s[t - off] : 0u;
        __syncthreads();
        s[t] += v;
        __syncthreads();
    }

    double y = 0.0;
    if (t < NBINS) {
        float invn = 1.0f / (float)n;
        float d = cp[t] * invn - (float)s[t] * invn;
        float yy = d * d;
        float w = (t == 0 || t == NBINS - 1) ? 0.5f : 1.0f;
        y = (double)yy * (double)w;
    }
    rd[t] = y;
    __syncthreads();
    for (int sft = 512; sft > 0; sft >>= 1) {
        if (t < sft) rd[t] += rd[t + sft];
        __syncthreads();
    }
    if (t == 0) {
        float lo = dec_f32(W[0]);
        float hi = dec_f32(W[1]);
        double dx = (double)(hi - lo) / (double)(NBINS - 1);
        out[0] = (float)(rd[0] * dx);
    }
}

extern "C" void kernel_launch(void* const* d_in, const int* in_sizes, int n_in,
                              void* d_out, int out_size, void* d_ws, size_t ws_size,
                              hipStream_t stream) {
    const float* p = (const float*)d_in[0];
    const float* t = (const float*)d_in[1];
    float* out = (float*)d_out;
    long long n = (long long)in_sizes[0];

    unsigned* W = (unsigned*)d_ws;

    init_kernel<<<1, 512, 0, stream>>>(W);
    minmax_kernel<<<2048, 256, 0, stream>>>(p, t, n, W);
    hist_kernel<<<1024, 256, 0, stream>>>(p, t, n, W);
    finalize_kernel<<<1, 1024, 0, stream>>>(W, out, n);
}